// Round 1
// 372.047 us; speedup vs baseline: 1.0048x; 1.0048x over previous
//
#include <hip/hip_runtime.h>

#define NN 8192
#define S1_BLOCKS 512
#define ROWS 16                 // rows per block -> 512 KB contiguous slab

// Stage 1 (UNCHANGED, measured ~43 us ~= HBM roofline for 268 MB):
// partial matvec, explicit row double-buffer to force MLP.
// Block b streams rows [b*16, b*16+16). 512 threads; thread t owns cols
// {t*4 + s*2048 : s=0..3} (4 float4 per row). Next row's 4 float4 are loaded
// into registers BEFORE current row's FMAs, so >=8 float4 stay in flight.
// Writes 8192 partial sums to ws[b*8192 + col]. No atomics.
__global__ __launch_bounds__(512) void partial_matvec(
    const float* __restrict__ ts,
    const float* __restrict__ state,
    float* __restrict__ ws)
{
    const int b = blockIdx.x;
    const int t = threadIdx.x;
    const int r0 = b * ROWS;

    float v[ROWS];
#pragma unroll
    for (int r = 0; r < ROWS; ++r)
        v[r] = state[3 * (r0 + r) + 2];         // block-uniform -> s_loads

    const float* base = ts + (size_t)r0 * NN + t * 4;

    float4 acc[4], cur[4];
#pragma unroll
    for (int s = 0; s < 4; ++s) {
        acc[s] = make_float4(0.f, 0.f, 0.f, 0.f);
        cur[s] = *(const float4*)(base + s * 2048);
    }

    for (int r = 0; r < ROWS - 1; ++r) {
        float4 nxt[4];
        const float* nrow = base + (size_t)(r + 1) * NN;
#pragma unroll
        for (int s = 0; s < 4; ++s)
            nxt[s] = *(const float4*)(nrow + s * 2048);
#pragma unroll
        for (int s = 0; s < 4; ++s) {
            acc[s].x += cur[s].x * v[r];
            acc[s].y += cur[s].y * v[r];
            acc[s].z += cur[s].z * v[r];
            acc[s].w += cur[s].w * v[r];
        }
#pragma unroll
        for (int s = 0; s < 4; ++s) cur[s] = nxt[s];
    }
#pragma unroll
    for (int s = 0; s < 4; ++s) {
        acc[s].x += cur[s].x * v[ROWS - 1];
        acc[s].y += cur[s].y * v[ROWS - 1];
        acc[s].z += cur[s].z * v[ROWS - 1];
        acc[s].w += cur[s].w * v[ROWS - 1];
    }

    float* wsb = ws + (size_t)b * NN + t * 4;
#pragma unroll
    for (int s = 0; s < 4; ++s)
        *(float4*)(wsb + s * 2048) = acc[s];
}

// Stage 2 v2: reduce 512 partials per column + ALL O(N) math fused.
// Old version used 64 blocks (64 CUs busy) -> per-CU BW bound, ~11 us for a
// 16.8 MB read. New: 256 blocks x 256 threads; block owns 32 columns
// (8 float4). 32 groups of 8 threads each sum 16 partial rows (float4-
// coalesced: each 8-lane group reads 128 B contiguous per partial row),
// LDS-reduce across groups, threads 0..31 finalize one column each.
// Summation order is unchanged (ascending partial rows: g ascending x k
// ascending == blocks ascending == rows ascending), so output stays
// bit-identical (absmax 0.0).
__global__ __launch_bounds__(256) void finalize_kernel(
    const float* __restrict__ ws,
    const float* __restrict__ state,
    const float* __restrict__ betas,
    const float* __restrict__ deltas,
    const float* __restrict__ cs,
    const float* __restrict__ ps,
    const float* __restrict__ ts,
    float* __restrict__ out)
{
    const int bb = blockIdx.x;          // 0..255, cols [bb*32, bb*32+32)
    const int t  = threadIdx.x;
    const int f4 = t & 7;               // float4 index within block's cols
    const int g  = t >> 3;              // partial-row group 0..31 (16 rows each)

    const float4* ws4 = (const float4*)ws;      // rows of 2048 float4
    const float4* p = ws4 + (size_t)(g * 16) * 2048 + bb * 8 + f4;

    float4 sum = make_float4(0.f, 0.f, 0.f, 0.f);
#pragma unroll
    for (int k = 0; k < 16; ++k) {
        float4 x = p[(size_t)k * 2048];
        sum.x += x.x; sum.y += x.y; sum.z += x.z; sum.w += x.w;
    }

    __shared__ float4 red[32][8];
    red[g][f4] = sum;
    __syncthreads();

    if (t < 32) {
        const int j = bb * 32 + t;
        float coupling = 0.f;
#pragma unroll
        for (int g2 = 0; g2 < 32; ++g2)
            coupling += ((const float*)&red[g2][t >> 2])[t & 3];

        float U = state[3 * j + 0];
        float I = state[3 * j + 1];
        float V = state[3 * j + 2];
        float beta  = betas[j]  * betas[j];
        float delta = deltas[j] * deltas[j];
        float c     = cs[j]     * cs[j];
        float pp    = ps[j]     * ps[j];
        float diag  = ts[(size_t)j * NN + j];
        float infect = beta * U * V;
        out[3 * j + 0] = -infect;
        out[3 * j + 1] = infect - delta * I;
        out[3 * j + 2] = pp * I - c * V - diag * V + coupling;
    }
}

extern "C" void kernel_launch(void* const* d_in, const int* in_sizes, int n_in,
                              void* d_out, int out_size, void* d_ws, size_t ws_size,
                              hipStream_t stream) {
    // setup_inputs order: t(0), state(1), betas(2), deltas(3), cs(4), ps(5), ts(6)
    const float* state  = (const float*)d_in[1];
    const float* betas  = (const float*)d_in[2];
    const float* deltas = (const float*)d_in[3];
    const float* cs     = (const float*)d_in[4];
    const float* ps     = (const float*)d_in[5];
    const float* ts     = (const float*)d_in[6];
    float* out = (float*)d_out;
    float* ws  = (float*)d_ws;          // 512*8192*4 = 16 MB used

    partial_matvec<<<S1_BLOCKS, 512, 0, stream>>>(ts, state, ws);
    finalize_kernel<<<NN / 32, 256, 0, stream>>>(ws, state, betas, deltas,
                                                 cs, ps, ts, out);
}